// Round 2
// baseline (180.746 us; speedup 1.0000x reference)
//
#include <hip/hip_runtime.h>

// SemiSparseCRFLoss on MI355X — fused single-kernel, float4-vectorized.
// Each thread processes one 8-pixel row segment; loads cur row + next row
// for y_pr(ch1) and 3 image channels as float4s. Last block finalizes.

#define BATCH 16
#define HGT 512
#define WID 512
#define HW (HGT * WID)
#define SEG 8
#define SEGS_PER_ROW (WID / SEG)            // 64
#define SEGS_PER_BATCH (HGT * SEGS_PER_ROW) // 32768 = 2^15
#define NSEG (BATCH * SEGS_PER_BATCH)       // 524288
#define NBLOCK (NSEG / 256)                 // 2048

__global__ __launch_bounds__(256) void crf_fused(
        const float* __restrict__ y_pr,
        const float* __restrict__ image,
        const int* __restrict__ image_class,
        double* __restrict__ acc,
        unsigned int* __restrict__ counter,
        float* __restrict__ out) {
    const float inv2s2 = 22.2222222f;    // 1/(2*0.15^2)
    const float wxy1 = 0.60653066f;      // exp(-1/2): shifts (0,1),(1,0)
    const float wxy2 = 0.36787944f;      // exp(-1):   shifts (1,1),(1,-1)

    const int idx = blockIdx.x * 256 + threadIdx.x;
    const int b = idx >> 15;                       // SEGS_PER_BATCH = 2^15
    double local = 0.0;

    if (image_class[b] != 0) {
        const int seg = idx & (SEGS_PER_BATCH - 1);
        const int h = seg >> 6;                    // SEGS_PER_ROW = 64
        const int w0 = (seg & 63) * SEG;
        const int hw = h * WID + w0;
        const bool hn = (h + 1 < HGT);
        const bool left = (w0 > 0);
        const bool right = (w0 + SEG < WID);

        const float* __restrict__ yb = y_pr + (size_t)b * 2 * HW + HW; // ch 1
        const float* __restrict__ ib = image + (size_t)b * 3 * HW;

        // Per-shift image-distance accumulators for the 8 pixels.
        float d2r[8], d2d[8], d2dr[8], d2dl[8];
        #pragma unroll
        for (int j = 0; j < 8; j++) { d2r[j] = 0.f; d2d[j] = 0.f; d2dr[j] = 0.f; d2dl[j] = 0.f; }

        #pragma unroll
        for (int c = 0; c < 3; c++) {
            const float* __restrict__ p = ib + c * HW + hw;
            float cur[9], nxt[10];
            {
                float4 a0 = *(const float4*)(p);
                float4 a1 = *(const float4*)(p + 4);
                cur[0] = a0.x; cur[1] = a0.y; cur[2] = a0.z; cur[3] = a0.w;
                cur[4] = a1.x; cur[5] = a1.y; cur[6] = a1.z; cur[7] = a1.w;
                cur[8] = right ? p[8] : 0.f;
            }
            if (hn) {
                float4 b0 = *(const float4*)(p + WID);
                float4 b1 = *(const float4*)(p + WID + 4);
                nxt[0] = left ? p[WID - 1] : 0.f;
                nxt[1] = b0.x; nxt[2] = b0.y; nxt[3] = b0.z; nxt[4] = b0.w;
                nxt[5] = b1.x; nxt[6] = b1.y; nxt[7] = b1.z; nxt[8] = b1.w;
                nxt[9] = right ? p[WID + 8] : 0.f;
            } else {
                #pragma unroll
                for (int k = 0; k < 10; k++) nxt[k] = 0.f;
            }
            #pragma unroll
            for (int j = 0; j < 8; j++) {
                // pixel col = w0+j; nxt[k] holds col w0-1+k
                float dr  = cur[j] - cur[j + 1];  d2r[j]  += dr  * dr;
                float dd  = cur[j] - nxt[j + 1];  d2d[j]  += dd  * dd;
                float ddr = cur[j] - nxt[j + 2];  d2dr[j] += ddr * ddr;
                float ddl = cur[j] - nxt[j];      d2dl[j] += ddl * ddl;
            }
        }

        float yc[9], yn[10];
        {
            const float* __restrict__ p = yb + hw;
            float4 a0 = *(const float4*)(p);
            float4 a1 = *(const float4*)(p + 4);
            yc[0] = a0.x; yc[1] = a0.y; yc[2] = a0.z; yc[3] = a0.w;
            yc[4] = a1.x; yc[5] = a1.y; yc[6] = a1.z; yc[7] = a1.w;
            yc[8] = right ? p[8] : 0.f;
            if (hn) {
                float4 b0 = *(const float4*)(p + WID);
                float4 b1 = *(const float4*)(p + WID + 4);
                yn[0] = left ? p[WID - 1] : 0.f;
                yn[1] = b0.x; yn[2] = b0.y; yn[3] = b0.z; yn[4] = b0.w;
                yn[5] = b1.x; yn[6] = b1.y; yn[7] = b1.z; yn[8] = b1.w;
                yn[9] = right ? p[WID + 8] : 0.f;
            } else {
                #pragma unroll
                for (int k = 0; k < 10; k++) yn[k] = 0.f;
            }
        }

        float s = 0.f;
        #pragma unroll
        for (int j = 0; j < 8; j++) {
            // shift (0,1): invalid only for last pixel of last segment
            if (j < 7 || right) {
                float dy = yc[j] - yc[j + 1];
                float m = expf(-d2r[j] * inv2s2) * wxy1 - 0.01f;
                s += m * dy * dy;
            }
            if (hn) {
                // shift (1,0)
                {
                    float dy = yc[j] - yn[j + 1];
                    float m = expf(-d2d[j] * inv2s2) * wxy1 - 0.01f;
                    s += m * dy * dy;
                }
                // shift (1,1)
                if (j < 7 || right) {
                    float dy = yc[j] - yn[j + 2];
                    float m = expf(-d2dr[j] * inv2s2) * wxy2 - 0.01f;
                    s += m * dy * dy;
                }
                // shift (1,-1)
                if (j > 0 || left) {
                    float dy = yc[j] - yn[j];
                    float m = expf(-d2dl[j] * inv2s2) * wxy2 - 0.01f;
                    s += m * dy * dy;
                }
            }
        }
        local = (double)s;
    }

    // wave64 reduction
    for (int off = 32; off > 0; off >>= 1)
        local += __shfl_down(local, off);

    __shared__ double sdata[4];
    const int lane = threadIdx.x & 63;
    const int wv = threadIdx.x >> 6;
    if (lane == 0) sdata[wv] = local;
    __syncthreads();
    if (threadIdx.x == 0) {
        double t = sdata[0] + sdata[1] + sdata[2] + sdata[3];
        atomicAdd(acc, t);
        __threadfence();
        unsigned int done = atomicAdd(counter, 1u);
        if (done == NBLOCK - 1) {
            // last block: all other acc adds are visible (fence + RMW chain)
            double tot = atomicAdd(acc, 0.0);
            out[0] = (float)(tot * (1.0 / ((double)HW * BATCH * 4)));
        }
    }
}

extern "C" void kernel_launch(void* const* d_in, const int* in_sizes, int n_in,
                              void* d_out, int out_size, void* d_ws, size_t ws_size,
                              hipStream_t stream) {
    const float* y_pr = (const float*)d_in[0];
    // d_in[1] (y_gt) unused by the reference
    const float* image = (const float*)d_in[2];
    const int* image_class = (const int*)d_in[3];
    float* out = (float*)d_out;
    double* acc = (double*)d_ws;
    unsigned int* counter = (unsigned int*)((char*)d_ws + 8);

    hipMemsetAsync(d_ws, 0, 16, stream);   // zero acc + counter (memset node)
    crf_fused<<<NBLOCK, 256, 0, stream>>>(y_pr, image, image_class,
                                          acc, counter, out);
}

// Round 3
// 117.289 us; speedup vs baseline: 1.5410x; 1.5410x over previous
//
#include <hip/hip_runtime.h>

// SemiSparseCRFLoss on MI355X — R3: atomic-free two-stage reduction.
// R2 post-mortem: single-address device atomics (2048-4096 per launch)
// serialized at ~35+ cyc each = the entire 60-95us kernel time. Replace
// with per-block partial stores + tiny reduce kernel.

#define BATCH 16
#define HGT 512
#define WID 512
#define HW (HGT * WID)
#define SEG 8
#define SEGS_PER_ROW (WID / SEG)            // 64
#define SEGS_PER_BATCH (HGT * SEGS_PER_ROW) // 32768 = 2^15
#define NSEG (BATCH * SEGS_PER_BATCH)       // 524288
#define NBLOCK (NSEG / 256)                 // 2048 (128 blocks per batch)

__global__ __launch_bounds__(256) void crf_map(
        const float* __restrict__ y_pr,
        const float* __restrict__ image,
        const int* __restrict__ image_class,
        double* __restrict__ partial) {
    const float inv2s2 = 22.2222222f;    // 1/(2*0.15^2)
    const float wxy1 = 0.60653066f;      // exp(-1/2): shifts (0,1),(1,0)
    const float wxy2 = 0.36787944f;      // exp(-1):   shifts (1,1),(1,-1)

    // b is uniform per block: 128 consecutive blocks per batch.
    const int b = blockIdx.x >> 7;
    double local = 0.0;

    if (image_class[b] != 0) {   // scalar branch: whole block skips
        const int idx = blockIdx.x * 256 + threadIdx.x;
        const int seg = idx & (SEGS_PER_BATCH - 1);
        const int h = seg >> 6;                    // SEGS_PER_ROW = 64
        const int w0 = (seg & 63) * SEG;
        const int hw = h * WID + w0;
        const bool hn = (h + 1 < HGT);
        const bool left = (w0 > 0);
        const bool right = (w0 + SEG < WID);

        const float* __restrict__ yb = y_pr + (size_t)b * 2 * HW + HW; // ch 1
        const float* __restrict__ ib = image + (size_t)b * 3 * HW;

        float d2r[8], d2d[8], d2dr[8], d2dl[8];
        #pragma unroll
        for (int j = 0; j < 8; j++) { d2r[j] = 0.f; d2d[j] = 0.f; d2dr[j] = 0.f; d2dl[j] = 0.f; }

        #pragma unroll
        for (int c = 0; c < 3; c++) {
            const float* __restrict__ p = ib + c * HW + hw;
            float cur[9], nxt[10];
            {
                float4 a0 = *(const float4*)(p);
                float4 a1 = *(const float4*)(p + 4);
                cur[0] = a0.x; cur[1] = a0.y; cur[2] = a0.z; cur[3] = a0.w;
                cur[4] = a1.x; cur[5] = a1.y; cur[6] = a1.z; cur[7] = a1.w;
                cur[8] = right ? p[8] : 0.f;
            }
            if (hn) {
                float4 b0 = *(const float4*)(p + WID);
                float4 b1 = *(const float4*)(p + WID + 4);
                nxt[0] = left ? p[WID - 1] : 0.f;
                nxt[1] = b0.x; nxt[2] = b0.y; nxt[3] = b0.z; nxt[4] = b0.w;
                nxt[5] = b1.x; nxt[6] = b1.y; nxt[7] = b1.z; nxt[8] = b1.w;
                nxt[9] = right ? p[WID + 8] : 0.f;
            } else {
                #pragma unroll
                for (int k = 0; k < 10; k++) nxt[k] = 0.f;
            }
            #pragma unroll
            for (int j = 0; j < 8; j++) {
                float dr  = cur[j] - cur[j + 1];  d2r[j]  += dr  * dr;
                float dd  = cur[j] - nxt[j + 1];  d2d[j]  += dd  * dd;
                float ddr = cur[j] - nxt[j + 2];  d2dr[j] += ddr * ddr;
                float ddl = cur[j] - nxt[j];      d2dl[j] += ddl * ddl;
            }
        }

        float yc[9], yn[10];
        {
            const float* __restrict__ p = yb + hw;
            float4 a0 = *(const float4*)(p);
            float4 a1 = *(const float4*)(p + 4);
            yc[0] = a0.x; yc[1] = a0.y; yc[2] = a0.z; yc[3] = a0.w;
            yc[4] = a1.x; yc[5] = a1.y; yc[6] = a1.z; yc[7] = a1.w;
            yc[8] = right ? p[8] : 0.f;
            if (hn) {
                float4 b0 = *(const float4*)(p + WID);
                float4 b1 = *(const float4*)(p + WID + 4);
                yn[0] = left ? p[WID - 1] : 0.f;
                yn[1] = b0.x; yn[2] = b0.y; yn[3] = b0.z; yn[4] = b0.w;
                yn[5] = b1.x; yn[6] = b1.y; yn[7] = b1.z; yn[8] = b1.w;
                yn[9] = right ? p[WID + 8] : 0.f;
            } else {
                #pragma unroll
                for (int k = 0; k < 10; k++) yn[k] = 0.f;
            }
        }

        float s = 0.f;
        #pragma unroll
        for (int j = 0; j < 8; j++) {
            if (j < 7 || right) {                  // shift (0,1)
                float dy = yc[j] - yc[j + 1];
                float m = expf(-d2r[j] * inv2s2) * wxy1 - 0.01f;
                s += m * dy * dy;
            }
            if (hn) {
                {                                   // shift (1,0)
                    float dy = yc[j] - yn[j + 1];
                    float m = expf(-d2d[j] * inv2s2) * wxy1 - 0.01f;
                    s += m * dy * dy;
                }
                if (j < 7 || right) {               // shift (1,1)
                    float dy = yc[j] - yn[j + 2];
                    float m = expf(-d2dr[j] * inv2s2) * wxy2 - 0.01f;
                    s += m * dy * dy;
                }
                if (j > 0 || left) {                // shift (1,-1)
                    float dy = yc[j] - yn[j];
                    float m = expf(-d2dl[j] * inv2s2) * wxy2 - 0.01f;
                    s += m * dy * dy;
                }
            }
        }
        local = (double)s;
    }

    // wave64 reduction
    for (int off = 32; off > 0; off >>= 1)
        local += __shfl_down(local, off);

    __shared__ double sdata[4];
    const int lane = threadIdx.x & 63;
    const int wv = threadIdx.x >> 6;
    if (lane == 0) sdata[wv] = local;
    __syncthreads();
    if (threadIdx.x == 0)
        partial[blockIdx.x] = sdata[0] + sdata[1] + sdata[2] + sdata[3];
}

__global__ __launch_bounds__(256) void crf_reduce(
        const double* __restrict__ partial, float* __restrict__ out) {
    double s = 0.0;
    for (int i = threadIdx.x; i < NBLOCK; i += 256)
        s += partial[i];
    for (int off = 32; off > 0; off >>= 1)
        s += __shfl_down(s, off);
    __shared__ double sdata[4];
    const int lane = threadIdx.x & 63;
    const int wv = threadIdx.x >> 6;
    if (lane == 0) sdata[wv] = s;
    __syncthreads();
    if (threadIdx.x == 0) {
        double t = sdata[0] + sdata[1] + sdata[2] + sdata[3];
        out[0] = (float)(t * (1.0 / ((double)HW * BATCH * 4)));
    }
}

extern "C" void kernel_launch(void* const* d_in, const int* in_sizes, int n_in,
                              void* d_out, int out_size, void* d_ws, size_t ws_size,
                              hipStream_t stream) {
    const float* y_pr = (const float*)d_in[0];
    // d_in[1] (y_gt) unused by the reference
    const float* image = (const float*)d_in[2];
    const int* image_class = (const int*)d_in[3];
    float* out = (float*)d_out;
    double* partial = (double*)d_ws;   // NBLOCK doubles = 16 KB

    crf_map<<<NBLOCK, 256, 0, stream>>>(y_pr, image, image_class, partial);
    crf_reduce<<<1, 256, 0, stream>>>(partial, out);
}

// Round 4
// 113.688 us; speedup vs baseline: 1.5898x; 1.0317x over previous
//
#include <hip/hip_runtime.h>

// SemiSparseCRFLoss on MI355X — R4: 2 segments/thread (grid-stride over
// batch halves), __expf fast path, atomic-free two-stage reduction.
// R3 post-mortem: ~97us of dur_us is harness reset (268MB ws re-poison =
// 41us fill + input restore); controllable part ~20us. This round targets
// the map kernel's latency-boundness (all pipes <10% busy).

#define BATCH 16
#define HGT 512
#define WID 512
#define HW (HGT * WID)
#define SEG 8
#define SEGS_PER_ROW (WID / SEG)            // 64
#define SEGS_PER_BATCH (HGT * SEGS_PER_ROW) // 32768 = 2^15
#define NSEG (BATCH * SEGS_PER_BATCH)       // 524288 = 2^19
#define NBLOCK 1024                          // each thread: 2 segments
#define BLOCKS_PER_BATCH 128                 // per batch-half

__device__ __forceinline__ float seg_loss(
        const float* __restrict__ yb,   // y_pr batch b, channel 1
        const float* __restrict__ ib,   // image batch b
        int seg) {
    const float inv2s2 = 22.2222222f;    // 1/(2*0.15^2)
    const float wxy1 = 0.60653066f;      // exp(-1/2): shifts (0,1),(1,0)
    const float wxy2 = 0.36787944f;      // exp(-1):   shifts (1,1),(1,-1)

    const int h = seg >> 6;
    const int w0 = (seg & 63) * SEG;
    const int hw = h * WID + w0;
    const bool hn = (h + 1 < HGT);
    const bool left = (w0 > 0);
    const bool right = (w0 + SEG < WID);

    float d2r[8], d2d[8], d2dr[8], d2dl[8];
    #pragma unroll
    for (int j = 0; j < 8; j++) { d2r[j] = 0.f; d2d[j] = 0.f; d2dr[j] = 0.f; d2dl[j] = 0.f; }

    #pragma unroll
    for (int c = 0; c < 3; c++) {
        const float* __restrict__ p = ib + c * HW + hw;
        float cur[9], nxt[10];
        {
            float4 a0 = *(const float4*)(p);
            float4 a1 = *(const float4*)(p + 4);
            cur[0] = a0.x; cur[1] = a0.y; cur[2] = a0.z; cur[3] = a0.w;
            cur[4] = a1.x; cur[5] = a1.y; cur[6] = a1.z; cur[7] = a1.w;
            cur[8] = right ? p[8] : 0.f;
        }
        if (hn) {
            float4 b0 = *(const float4*)(p + WID);
            float4 b1 = *(const float4*)(p + WID + 4);
            nxt[0] = left ? p[WID - 1] : 0.f;
            nxt[1] = b0.x; nxt[2] = b0.y; nxt[3] = b0.z; nxt[4] = b0.w;
            nxt[5] = b1.x; nxt[6] = b1.y; nxt[7] = b1.z; nxt[8] = b1.w;
            nxt[9] = right ? p[WID + 8] : 0.f;
        } else {
            #pragma unroll
            for (int k = 0; k < 10; k++) nxt[k] = 0.f;
        }
        #pragma unroll
        for (int j = 0; j < 8; j++) {
            float dr  = cur[j] - cur[j + 1];  d2r[j]  += dr  * dr;
            float dd  = cur[j] - nxt[j + 1];  d2d[j]  += dd  * dd;
            float ddr = cur[j] - nxt[j + 2];  d2dr[j] += ddr * ddr;
            float ddl = cur[j] - nxt[j];      d2dl[j] += ddl * ddl;
        }
    }

    float yc[9], yn[10];
    {
        const float* __restrict__ p = yb + hw;
        float4 a0 = *(const float4*)(p);
        float4 a1 = *(const float4*)(p + 4);
        yc[0] = a0.x; yc[1] = a0.y; yc[2] = a0.z; yc[3] = a0.w;
        yc[4] = a1.x; yc[5] = a1.y; yc[6] = a1.z; yc[7] = a1.w;
        yc[8] = right ? p[8] : 0.f;
        if (hn) {
            float4 b0 = *(const float4*)(p + WID);
            float4 b1 = *(const float4*)(p + WID + 4);
            yn[0] = left ? p[WID - 1] : 0.f;
            yn[1] = b0.x; yn[2] = b0.y; yn[3] = b0.z; yn[4] = b0.w;
            yn[5] = b1.x; yn[6] = b1.y; yn[7] = b1.z; yn[8] = b1.w;
            yn[9] = right ? p[WID + 8] : 0.f;
        } else {
            #pragma unroll
            for (int k = 0; k < 10; k++) yn[k] = 0.f;
        }
    }

    float s = 0.f;
    #pragma unroll
    for (int j = 0; j < 8; j++) {
        if (j < 7 || right) {                  // shift (0,1)
            float dy = yc[j] - yc[j + 1];
            float m = __expf(-d2r[j] * inv2s2) * wxy1 - 0.01f;
            s += m * dy * dy;
        }
        if (hn) {
            {                                   // shift (1,0)
                float dy = yc[j] - yn[j + 1];
                float m = __expf(-d2d[j] * inv2s2) * wxy1 - 0.01f;
                s += m * dy * dy;
            }
            if (j < 7 || right) {               // shift (1,1)
                float dy = yc[j] - yn[j + 2];
                float m = __expf(-d2dr[j] * inv2s2) * wxy2 - 0.01f;
                s += m * dy * dy;
            }
            if (j > 0 || left) {                // shift (1,-1)
                float dy = yc[j] - yn[j];
                float m = __expf(-d2dl[j] * inv2s2) * wxy2 - 0.01f;
                s += m * dy * dy;
            }
        }
    }
    return s;
}

__global__ __launch_bounds__(256) void crf_map(
        const float* __restrict__ y_pr,
        const float* __restrict__ image,
        const int* __restrict__ image_class,
        double* __restrict__ partial) {
    // tid in [0, NSEG/2): batch-half 0 covers b=0..7, half 1 covers b=8..15.
    const int tid = blockIdx.x * 256 + threadIdx.x;
    const int seg = tid & (SEGS_PER_BATCH - 1);
    const int b0 = blockIdx.x >> 7;           // wave-uniform, in [0,8)
    const int b1 = b0 + 8;

    double local = 0.0;
    if (image_class[b0] != 0) {
        const float* yb = y_pr + (size_t)b0 * 2 * HW + HW;
        const float* ib = image + (size_t)b0 * 3 * HW;
        local += (double)seg_loss(yb, ib, seg);
    }
    if (image_class[b1] != 0) {
        const float* yb = y_pr + (size_t)b1 * 2 * HW + HW;
        const float* ib = image + (size_t)b1 * 3 * HW;
        local += (double)seg_loss(yb, ib, seg);
    }

    // wave64 reduction
    for (int off = 32; off > 0; off >>= 1)
        local += __shfl_down(local, off);

    __shared__ double sdata[4];
    const int lane = threadIdx.x & 63;
    const int wv = threadIdx.x >> 6;
    if (lane == 0) sdata[wv] = local;
    __syncthreads();
    if (threadIdx.x == 0)
        partial[blockIdx.x] = sdata[0] + sdata[1] + sdata[2] + sdata[3];
}

__global__ __launch_bounds__(256) void crf_reduce(
        const double* __restrict__ partial, float* __restrict__ out) {
    double s = 0.0;
    for (int i = threadIdx.x; i < NBLOCK; i += 256)
        s += partial[i];
    for (int off = 32; off > 0; off >>= 1)
        s += __shfl_down(s, off);
    __shared__ double sdata[4];
    const int lane = threadIdx.x & 63;
    const int wv = threadIdx.x >> 6;
    if (lane == 0) sdata[wv] = s;
    __syncthreads();
    if (threadIdx.x == 0) {
        double t = sdata[0] + sdata[1] + sdata[2] + sdata[3];
        out[0] = (float)(t * (1.0 / ((double)HW * BATCH * 4)));
    }
}

extern "C" void kernel_launch(void* const* d_in, const int* in_sizes, int n_in,
                              void* d_out, int out_size, void* d_ws, size_t ws_size,
                              hipStream_t stream) {
    const float* y_pr = (const float*)d_in[0];
    // d_in[1] (y_gt) unused by the reference
    const float* image = (const float*)d_in[2];
    const int* image_class = (const int*)d_in[3];
    float* out = (float*)d_out;
    double* partial = (double*)d_ws;   // NBLOCK doubles = 8 KB

    crf_map<<<NBLOCK, 256, 0, stream>>>(y_pr, image, image_class, partial);
    crf_reduce<<<1, 256, 0, stream>>>(partial, out);
}